// Round 2
// baseline (195.344 us; speedup 1.0000x reference)
//
#include <hip/hip_runtime.h>
#include <hip/hip_bf16.h>
#include <math.h>

#define NB  32
#define NS  4096
#define ND  64
#define NKC 256

// proj_gemm tiling
#define BK   128   // K (seq) step per iteration
#define ASA  132   // As row stride (shorts): 128 data + 4 pad (264 B rows, ~2-way reads)
#define ASB  132   // Bs row stride (shorts)

// attn_fused LDS strides (unchanged from previous version)
#define QSTR  72   // Qs row stride (bf16): 144 B, 16B-aligned
#define PBSTR 264  // bf16 prob stride (shorts)
#define VSTR  264  // bf16 VfT stride (shorts)

typedef __attribute__((ext_vector_type(8))) short short8;
typedef __attribute__((ext_vector_type(4))) float f32x4;

__device__ __forceinline__ short f2bf(float f) {
    union { float f; unsigned u; } v; v.f = f;
    return (short)((v.u + 0x7FFFu + ((v.u >> 16) & 1u)) >> 16);  // RTNE
}

// ---------------------------------------------------------------------------
// prep: convert Ew/Fw fp32 -> bf16. No accumulator zeroing anymore (proj does
// plain stores, not atomics). 1024 blocks x 256 threads x 8 elems = 2M elems.
// ---------------------------------------------------------------------------
__global__ __launch_bounds__(256) void prep(
    const float* __restrict__ Ew, const float* __restrict__ Fw,
    short* __restrict__ EwB, short* __restrict__ FwB)
{
    const int gid = blockIdx.x * 256 + threadIdx.x;       // < 262144
    const int half = (NKC * NS) / 8;                      // 131072
    const float* src = (gid < half) ? Ew : Fw;
    short* dst       = (gid < half) ? EwB : FwB;
    const int i8 = (gid < half) ? gid : gid - half;
    float4 a = *(const float4*)&src[(size_t)i8 * 8];
    float4 c = *(const float4*)&src[(size_t)i8 * 8 + 4];
    short8 w;
    w[0] = f2bf(a.x); w[1] = f2bf(a.y); w[2] = f2bf(a.z); w[3] = f2bf(a.w);
    w[4] = f2bf(c.x); w[5] = f2bf(c.y); w[6] = f2bf(c.z); w[7] = f2bf(c.w);
    *(short8*)&dst[(size_t)i8 * 8] = w;
}

// ---------------------------------------------------------------------------
// proj v2: M-split, full-K, NO atomics. Each block owns 64 kc rows x 64 d
// for one (b, mm) and reduces the full S=4096 in 32 iterations of BK=128,
// then stores its tile exactly once.
//
// Grid: 1-D, 256 blocks. bid = G*32 + mt*8 + r8, with g = G*8 + r8 = b*2+mm.
//  - the 4 mtile-blocks of one (b,mm) have bids == r8 (mod 8) -> same XCD
//    (linear%8 heuristic): the 1 MB K/V slab is fetched once per XCD and
//    served from L2 to all 4 sharers.
//  - per XCD: all 4 A mtiles (2 MB bf16 total) -> L2-resident; r8 parity
//    fixes mm, so each XCD streams only K or only V.
// AT = short (preconverted bf16 weights) or float (convert in staging).
// ---------------------------------------------------------------------------
template <typename AT>
__global__ __launch_bounds__(256) void proj_gemm(
    const AT* __restrict__ EwX, const AT* __restrict__ FwX,
    const float* __restrict__ K, const float* __restrict__ V,
    float* __restrict__ KeT, float* __restrict__ Vf)
{
    const int bid = blockIdx.x;
    const int r8 = bid & 7, mt = (bid >> 3) & 3, G = bid >> 5;
    const int g  = G * 8 + r8, b = g >> 1, mm = g & 1;

    const AT* __restrict__ Ab    = mm ? FwX : EwX;  // [256][4096]
    const float* __restrict__ Bg = mm ? V   : K;    // [B][4096][64] fp32
    float* __restrict__ Cout     = mm ? Vf  : KeT;  // [B][256][64] fp32

    const int t = threadIdx.x, wave = t >> 6, lane = t & 63;
    const int lm = lane & 15, g4 = lane >> 4;
    __shared__ short As[64 * ASA];   // 16896 B, rows = kc (local), cols = s
    __shared__ short Bs[64 * ASB];   // 16896 B, rows = d,          cols = s
    const size_t bBase = (size_t)b * NS * ND;
    const size_t aBase = (size_t)mt * 64 * NS;
    const int rA = t >> 4, jA = t & 15;  // A staging: 16 rows/pass, 16 col-octets
    const int dB = t & 31, sB = t >> 5;  // B staging: d-pair, s-octet group

    f32x4 acc[4];
#pragma unroll
    for (int nt = 0; nt < 4; ++nt) acc[nt] = (f32x4){0.f, 0.f, 0.f, 0.f};

    short8 pa[4];      // bf16-A path: 4 x 16B = row octets
    float4 paf[8];     // fp32-A path
    float2 pb[16];     // B: 16 s-rows' d-pairs (two 64-row halves)

    // prologue prefetch (iter 0)
#pragma unroll
    for (int i = 0; i < 4; ++i) {
        if constexpr (sizeof(AT) == 2) {
            pa[i] = *(const short8*)&Ab[aBase + (size_t)(i * 16 + rA) * NS + jA * 8];
        } else {
            paf[2 * i]     = *(const float4*)&Ab[aBase + (size_t)(i * 16 + rA) * NS + jA * 8];
            paf[2 * i + 1] = *(const float4*)&Ab[aBase + (size_t)(i * 16 + rA) * NS + jA * 8 + 4];
        }
    }
#pragma unroll
    for (int h = 0; h < 2; ++h)
#pragma unroll
        for (int i = 0; i < 8; ++i)
            pb[h * 8 + i] = *(const float2*)&Bg[bBase + (size_t)(h * 64 + sB * 8 + i) * ND + dB * 2];

    for (int s0 = 0; s0 < NS; s0 += BK) {
        // ---- stage regs -> LDS (iter s0 data) ----
#pragma unroll
        for (int i = 0; i < 4; ++i) {
            if constexpr (sizeof(AT) == 2) {
                *(short8*)&As[(i * 16 + rA) * ASA + jA * 8] = pa[i];
            } else {
                short8 w;
                w[0] = f2bf(paf[2 * i].x);     w[1] = f2bf(paf[2 * i].y);
                w[2] = f2bf(paf[2 * i].z);     w[3] = f2bf(paf[2 * i].w);
                w[4] = f2bf(paf[2 * i + 1].x); w[5] = f2bf(paf[2 * i + 1].y);
                w[6] = f2bf(paf[2 * i + 1].z); w[7] = f2bf(paf[2 * i + 1].w);
                *(short8*)&As[(i * 16 + rA) * ASA + jA * 8] = w;
            }
        }
#pragma unroll
        for (int h = 0; h < 2; ++h) {
            short8 w0, w1;
#pragma unroll
            for (int i = 0; i < 8; ++i) {
                w0[i] = f2bf(pb[h * 8 + i].x);
                w1[i] = f2bf(pb[h * 8 + i].y);
            }
            *(short8*)&Bs[(dB * 2 + 0) * ASB + h * 64 + sB * 8] = w0;
            *(short8*)&Bs[(dB * 2 + 1) * ASB + h * 64 + sB * 8] = w1;
        }
        __syncthreads();

        // ---- issue next-iter global loads (land during MFMA below) ----
        if (s0 + BK < NS) {
            const int sn = s0 + BK;
#pragma unroll
            for (int i = 0; i < 4; ++i) {
                if constexpr (sizeof(AT) == 2) {
                    pa[i] = *(const short8*)&Ab[aBase + (size_t)(i * 16 + rA) * NS + sn + jA * 8];
                } else {
                    paf[2 * i]     = *(const float4*)&Ab[aBase + (size_t)(i * 16 + rA) * NS + sn + jA * 8];
                    paf[2 * i + 1] = *(const float4*)&Ab[aBase + (size_t)(i * 16 + rA) * NS + sn + jA * 8 + 4];
                }
            }
#pragma unroll
            for (int h = 0; h < 2; ++h)
#pragma unroll
                for (int i = 0; i < 8; ++i)
                    pb[h * 8 + i] = *(const float2*)&Bg[bBase + (size_t)(sn + h * 64 + sB * 8 + i) * ND + dB * 2];
        }

        // ---- MFMA over BK=128 (4 k-steps of 32) ----
#pragma unroll
        for (int ks = 0; ks < BK; ks += 32) {
            short8 aF = *(const short8*)&As[(wave * 16 + lm) * ASA + ks + g4 * 8];
#pragma unroll
            for (int nt = 0; nt < 4; ++nt) {
                short8 bF = *(const short8*)&Bs[(nt * 16 + lm) * ASB + ks + g4 * 8];
                acc[nt] = __builtin_amdgcn_mfma_f32_16x16x32_bf16(aF, bF, acc[nt], 0, 0, 0);
            }
        }
        __syncthreads();
    }

    // ---- epilogue: plain stores, each output element written exactly once ----
#pragma unroll
    for (int nt = 0; nt < 4; ++nt)
#pragma unroll
        for (int rr = 0; rr < 4; ++rr) {
            int kc = mt * 64 + wave * 16 + g4 * 4 + rr;
            Cout[((size_t)b * NKC + kc) * ND + nt * 16 + lm] = acc[nt][rr];
        }
}

// ---------------------------------------------------------------------------
// attn_fused: x<8 -> MFMA attention rows x*32..+31 (bias + bf16 inline,
// max-free softmax); x>=8 -> mean-broadcast, 64 rows/block. grid (68, 32).
// ---------------------------------------------------------------------------
__global__ __launch_bounds__(256) void attn_fused(
    const float* __restrict__ Q,  const float* __restrict__ KeT,
    const float* __restrict__ Vf, const float* __restrict__ Eb,
    const float* __restrict__ Fb, float* __restrict__ out)
{
    const int x = blockIdx.x, b = blockIdx.y, t = threadIdx.x;

    if (x >= 8) {
        // rows >= 256 fully masked -> uniform softmax -> mean_k (Vf[k,:]+Fb[k])
        __shared__ float pq[16][64];
        __shared__ float mv[64];
        const int kg = t >> 4, dq = t & 15;
        float4 s4 = (float4){0.f, 0.f, 0.f, 0.f};
        for (int p = 0; p < 16; ++p) {
            int k = p * 16 + kg;
            float4 v = *(const float4*)&Vf[((size_t)b * NKC + k) * ND + dq * 4];
            float fb = Fb[k];
            s4.x += v.x + fb; s4.y += v.y + fb; s4.z += v.z + fb; s4.w += v.w + fb;
        }
        *(float4*)&pq[kg][dq * 4] = s4;
        __syncthreads();
        if (t < 64) {
            float m = 0.f;
#pragma unroll
            for (int i = 0; i < 16; ++i) m += pq[i][t];
            mv[t] = m * (1.f / 256.f);
        }
        __syncthreads();
        const int r0 = 256 + (x - 8) * 64;
#pragma unroll
        for (int i = 0; i < 4; ++i) {      // 4*256 float4 = 64 rows
            int idx = i * 256 + t, row = idx >> 4, q = idx & 15;
            *(float4*)&out[((size_t)b * NS + r0 + row) * ND + q * 4] =
                *(const float4*)&mv[q * 4];
        }
        return;
    }

    const int s0 = x * 32;
    const int wave = t >> 6, lane = t & 63, lm = lane & 15, g = lane >> 4;
    __shared__ short Qs[32 * QSTR];     //  4.6 KB
    __shared__ short PsB[32 * PBSTR];   // 16.9 KB
    __shared__ short VfT[64 * VSTR];    // 33.8 KB
    __shared__ float rsums[32][4];      // [row][wave]

    // stage Q rows -> bf16
    {
        int row = t >> 3, dq = t & 7;
        size_t off = ((size_t)b * NS + s0 + row) * ND + dq * 8;
        float4 q0 = *(const float4*)&Q[off], q1 = *(const float4*)&Q[off + 4];
        short8 w;
        w[0] = f2bf(q0.x); w[1] = f2bf(q0.y); w[2] = f2bf(q0.z); w[3] = f2bf(q0.w);
        w[4] = f2bf(q1.x); w[5] = f2bf(q1.y); w[6] = f2bf(q1.z); w[7] = f2bf(q1.w);
        *(short8*)&Qs[row * QSTR + dq * 8] = w;
    }
    // stage VfT[d][k] = bf16(Vf[k][d] + Fb[k]); 4 passes of 64 k-rows
    {
        const int dB = t & 31, sB = t >> 5;
#pragma unroll
        for (int pass = 0; pass < 4; ++pass) {
            int kb = pass * 64 + sB * 8;
            float2 v[8]; float fb[8];
#pragma unroll
            for (int i = 0; i < 8; ++i) {
                v[i]  = *(const float2*)&Vf[((size_t)b * NKC + kb + i) * ND + dB * 2];
                fb[i] = Fb[kb + i];
            }
            short8 w0, w1;
#pragma unroll
            for (int i = 0; i < 8; ++i) {
                w0[i] = f2bf(v[i].x + fb[i]);
                w1[i] = f2bf(v[i].y + fb[i]);
            }
            *(short8*)&VfT[(dB * 2 + 0) * VSTR + kb] = w0;
            *(short8*)&VfT[(dB * 2 + 1) * VSTR + kb] = w1;
        }
    }
    __syncthreads();

    // phase 1: P = Q*(Ke+Eb)^T/8; wave w -> col range [w*64, w*64+64)
    f32x4 accP[2][4];
#pragma unroll
    for (int rt = 0; rt < 2; ++rt)
#pragma unroll
        for (int kk = 0; kk < 4; ++kk) accP[rt][kk] = (f32x4){0.f, 0.f, 0.f, 0.f};
#pragma unroll
    for (int kk = 0; kk < 4; ++kk) {
        int kt = wave * 4 + kk;
        float ebv = Eb[kt * 16 + lm];
#pragma unroll
        for (int ks2 = 0; ks2 < 2; ++ks2) {
            const float* kp = &KeT[((size_t)b * NKC + kt * 16 + lm) * ND + ks2 * 32 + g * 8];
            float4 c0 = *(const float4*)kp, c1 = *(const float4*)(kp + 4);
            short8 bf;
            bf[0] = f2bf(c0.x + ebv); bf[1] = f2bf(c0.y + ebv);
            bf[2] = f2bf(c0.z + ebv); bf[3] = f2bf(c0.w + ebv);
            bf[4] = f2bf(c1.x + ebv); bf[5] = f2bf(c1.y + ebv);
            bf[6] = f2bf(c1.z + ebv); bf[7] = f2bf(c1.w + ebv);
#pragma unroll
            for (int rt = 0; rt < 2; ++rt) {
                short8 aq = *(const short8*)&Qs[(rt * 16 + lm) * QSTR + ks2 * 32 + g * 8];
                accP[rt][kk] = __builtin_amdgcn_mfma_f32_16x16x32_bf16(aq, bf, accP[rt][kk], 0, 0, 0);
            }
        }
    }
    // exp (max-free: scores ~ N(0,1), no overflow) + per-row partial sums
#pragma unroll
    for (int rt = 0; rt < 2; ++rt)
#pragma unroll
        for (int r = 0; r < 4; ++r) {
            float s = 0.f;
            int rowg = s0 + rt * 16 + g * 4 + r;
#pragma unroll
            for (int kk = 0; kk < 4; ++kk) {
                int col = wave * 64 + kk * 16 + lm;
                float e = (col >= rowg) ? __expf(accP[rt][kk][r] * 0.125f) : 0.f;
                accP[rt][kk][r] = e;
                s += e;
            }
#pragma unroll
            for (int off = 1; off <= 8; off <<= 1) s += __shfl_xor(s, off, 64);
            if (lm == 0) rsums[rt * 16 + g * 4 + r][wave] = s;
        }
    __syncthreads();
    // normalize -> PsB bf16
#pragma unroll
    for (int rt = 0; rt < 2; ++rt)
#pragma unroll
        for (int r = 0; r < 4; ++r) {
            float4 rs = *(const float4*)&rsums[rt * 16 + g * 4 + r][0];
            float inv = 1.f / (rs.x + rs.y + rs.z + rs.w);
#pragma unroll
            for (int kk = 0; kk < 4; ++kk)
                PsB[(rt * 16 + g * 4 + r) * PBSTR + wave * 64 + kk * 16 + lm] =
                    f2bf(accP[rt][kk][r] * inv);
        }
    __syncthreads();

    // phase 2: out = P * VfT; k < 32x provably zero -> start at ks = x
    f32x4 oa[2];
    oa[0] = (f32x4){0.f, 0.f, 0.f, 0.f};
    oa[1] = (f32x4){0.f, 0.f, 0.f, 0.f};
    for (int ks = x; ks < 8; ++ks) {
        short8 bv = *(const short8*)&VfT[(wave * 16 + lm) * VSTR + ks * 32 + g * 8];
#pragma unroll
        for (int rt = 0; rt < 2; ++rt) {
            short8 av = *(const short8*)&PsB[(rt * 16 + lm) * PBSTR + ks * 32 + g * 8];
            oa[rt] = __builtin_amdgcn_mfma_f32_16x16x32_bf16(av, bv, oa[rt], 0, 0, 0);
        }
    }
#pragma unroll
    for (int rt = 0; rt < 2; ++rt)
#pragma unroll
        for (int r = 0; r < 4; ++r)
            out[((size_t)b * NS + s0 + rt * 16 + g * 4 + r) * ND + wave * 16 + lm] = oa[rt][r];
}

extern "C" void kernel_launch(void* const* d_in, const int* in_sizes, int n_in,
                              void* d_out, int out_size, void* d_ws, size_t ws_size,
                              hipStream_t stream) {
    (void)in_sizes; (void)n_in; (void)out_size;
    const float* Q  = (const float*)d_in[0];
    const float* K  = (const float*)d_in[1];
    const float* V  = (const float*)d_in[2];
    const float* Ew = (const float*)d_in[3];
    const float* Eb = (const float*)d_in[4];
    const float* Fw = (const float*)d_in[5];
    const float* Fb = (const float*)d_in[6];
    float* out = (float*)d_out;

    const size_t nKe = (size_t)NB * NKC * ND;       // 524288
    float* KeT = (float*)d_ws;                      // 2 MB fp32 (written once)
    float* Vf  = KeT + nKe;                         // 2 MB fp32 (written once)

    if (ws_size >= 8u * 1024 * 1024) {
        short* EwB = (short*)(Vf + nKe);            // 2 MB bf16 weights
        short* FwB = EwB + (size_t)NKC * NS;        // 2 MB bf16 weights
        prep<<<dim3(1024), 256, 0, stream>>>(Ew, Fw, EwB, FwB);
        proj_gemm<short><<<dim3(256), 256, 0, stream>>>(EwB, FwB, K, V, KeT, Vf);
    } else {
        // no zero-init needed: proj writes every output element exactly once
        proj_gemm<float><<<dim3(256), 256, 0, stream>>>(Ew, Fw, K, V, KeT, Vf);
    }
    attn_fused<<<dim3(68, NB), 256, 0, stream>>>(Q, KeT, Vf, Eb, Fb, out);
}

// Round 3
// 193.266 us; speedup vs baseline: 1.0108x; 1.0108x over previous
//
#include <hip/hip_runtime.h>
#include <hip/hip_bf16.h>
#include <math.h>

#define NB  32
#define NS  4096
#define ND  64
#define NKC 256

// proj_gemm tiling: 512 blocks x 512 threads, block tile 32kc x 64d, full K
#define BK   128   // K (seq) step per iteration
#define ASA  132   // As row stride (shorts): 128 data + 4 pad (264 B rows, ~2-way)
#define ASB  132   // Bs row stride (shorts)

// attn_fused LDS strides (unchanged)
#define QSTR  72   // Qs row stride (bf16): 144 B, 16B-aligned
#define PBSTR 264  // bf16 prob stride (shorts)
#define VSTR  264  // bf16 VfT stride (shorts)

typedef __attribute__((ext_vector_type(8))) short short8;
typedef __attribute__((ext_vector_type(4))) float f32x4;

__device__ __forceinline__ short f2bf(float f) {
    union { float f; unsigned u; } v; v.f = f;
    return (short)((v.u + 0x7FFFu + ((v.u >> 16) & 1u)) >> 16);  // RTNE
}

// ---------------------------------------------------------------------------
// prep: convert Ew/Fw fp32 -> bf16 (no accumulator zeroing; proj uses plain
// stores). 1024 blocks x 256 threads x 8 elems = 2M elems.
// ---------------------------------------------------------------------------
__global__ __launch_bounds__(256) void prep(
    const float* __restrict__ Ew, const float* __restrict__ Fw,
    short* __restrict__ EwB, short* __restrict__ FwB)
{
    const int gid = blockIdx.x * 256 + threadIdx.x;       // < 262144
    const int half = (NKC * NS) / 8;                      // 131072
    const float* src = (gid < half) ? Ew : Fw;
    short* dst       = (gid < half) ? EwB : FwB;
    const int i8 = (gid < half) ? gid : gid - half;
    float4 a = *(const float4*)&src[(size_t)i8 * 8];
    float4 c = *(const float4*)&src[(size_t)i8 * 8 + 4];
    short8 w;
    w[0] = f2bf(a.x); w[1] = f2bf(a.y); w[2] = f2bf(a.z); w[3] = f2bf(a.w);
    w[4] = f2bf(c.x); w[5] = f2bf(c.y); w[6] = f2bf(c.z); w[7] = f2bf(c.w);
    *(short8*)&dst[(size_t)i8 * 8] = w;
}

// ---------------------------------------------------------------------------
// proj v3: M-split, full-K, no atomics, HIGH OCCUPANCY.
// Grid 512 blocks x 512 threads: block tile = 32 kc x 64 d for one (b,mm),
// 32 iterations of BK=128. 2 blocks/CU x 8 waves = 16 waves/CU (4/SIMD);
// the two co-resident blocks have independent barriers -> cross-block overlap.
//
// bid = G*64 + mt*8 + r8:  r8 = XCD slot, mt = kc-tile (0..7), G -> (b,mm).
//  - blocks sharing one (b,mm) B-slab (8 of them) have bid%8 == r8 -> same
//    XCD; B slab (1 MB fp32) fetched once per XCD, L2-served to 8 sharers.
//  - r8 parity fixes mm: each XCD streams only K or only V; its A mtiles
//    (2 MB bf16 total) stay L2-resident.
// AT = short (preconverted bf16 weights) or float (convert in staging).
// ---------------------------------------------------------------------------
template <typename AT>
__global__ __launch_bounds__(512, 4) void proj_gemm(
    const AT* __restrict__ EwX, const AT* __restrict__ FwX,
    const float* __restrict__ K, const float* __restrict__ V,
    float* __restrict__ KeT, float* __restrict__ Vf)
{
    const int bid = blockIdx.x;
    const int r8 = bid & 7, mt = (bid >> 3) & 7, G = bid >> 6;
    const int g  = G * 8 + r8, b = g >> 1, mm = g & 1;

    const AT* __restrict__ Ab    = mm ? FwX : EwX;  // [256][4096]
    const float* __restrict__ Bg = mm ? V   : K;    // [B][4096][64] fp32
    float* __restrict__ Cout     = mm ? Vf  : KeT;  // [B][256][64] fp32

    const int t = threadIdx.x, wave = t >> 6, lane = t & 63;
    const int lm = lane & 15, g4 = lane >> 4;
    const int kcT = wave & 1, dT = wave >> 1;       // wave tile: 16kc x 16d
    __shared__ short As[32 * ASA];   //  8448 B, rows = kc (local), cols = s
    __shared__ short Bs[64 * ASB];   // 16896 B, rows = d,          cols = s
    const size_t bBase = (size_t)b * NS * ND;
    const size_t aBase = (size_t)mt * 32 * NS;
    const int rA = t >> 4, jA = t & 15;  // A staging: row 0..31, col-octet 0..15
    const int dB = t & 31, sB = t >> 5;  // B staging: d-pair, s-octet (0..15)

    f32x4 acc = (f32x4){0.f, 0.f, 0.f, 0.f};

    short8 pa;         // bf16-A path: 1 x 16B
    float4 paf[2];     // fp32-A path
    float2 pb[8];      // B: 8 s-rows' d-pairs

    // prologue prefetch (iter 0)
    if constexpr (sizeof(AT) == 2) {
        pa = *(const short8*)&Ab[aBase + (size_t)rA * NS + jA * 8];
    } else {
        paf[0] = *(const float4*)&Ab[aBase + (size_t)rA * NS + jA * 8];
        paf[1] = *(const float4*)&Ab[aBase + (size_t)rA * NS + jA * 8 + 4];
    }
#pragma unroll
    for (int i = 0; i < 8; ++i)
        pb[i] = *(const float2*)&Bg[bBase + (size_t)(sB * 8 + i) * ND + dB * 2];

    for (int s0 = 0; s0 < NS; s0 += BK) {
        // ---- stage regs -> LDS (iter s0 data) ----
        if constexpr (sizeof(AT) == 2) {
            *(short8*)&As[rA * ASA + jA * 8] = pa;
        } else {
            short8 w;
            w[0] = f2bf(paf[0].x); w[1] = f2bf(paf[0].y);
            w[2] = f2bf(paf[0].z); w[3] = f2bf(paf[0].w);
            w[4] = f2bf(paf[1].x); w[5] = f2bf(paf[1].y);
            w[6] = f2bf(paf[1].z); w[7] = f2bf(paf[1].w);
            *(short8*)&As[rA * ASA + jA * 8] = w;
        }
        {
            short8 w0, w1;
#pragma unroll
            for (int i = 0; i < 8; ++i) { w0[i] = f2bf(pb[i].x); w1[i] = f2bf(pb[i].y); }
            *(short8*)&Bs[(dB * 2 + 0) * ASB + sB * 8] = w0;
            *(short8*)&Bs[(dB * 2 + 1) * ASB + sB * 8] = w1;
        }
        __syncthreads();

        // ---- issue next-iter global loads (land during MFMA below) ----
        if (s0 + BK < NS) {
            const int sn = s0 + BK;
            if constexpr (sizeof(AT) == 2) {
                pa = *(const short8*)&Ab[aBase + (size_t)rA * NS + sn + jA * 8];
            } else {
                paf[0] = *(const float4*)&Ab[aBase + (size_t)rA * NS + sn + jA * 8];
                paf[1] = *(const float4*)&Ab[aBase + (size_t)rA * NS + sn + jA * 8 + 4];
            }
#pragma unroll
            for (int i = 0; i < 8; ++i)
                pb[i] = *(const float2*)&Bg[bBase + (size_t)(sn + sB * 8 + i) * ND + dB * 2];
        }

        // ---- MFMA over BK=128 (4 k-steps of 32), one 16x16 tile per wave ----
#pragma unroll
        for (int ks = 0; ks < BK; ks += 32) {
            short8 aF = *(const short8*)&As[(kcT * 16 + lm) * ASA + ks + g4 * 8];
            short8 bF = *(const short8*)&Bs[(dT * 16 + lm) * ASB + ks + g4 * 8];
            acc = __builtin_amdgcn_mfma_f32_16x16x32_bf16(aF, bF, acc, 0, 0, 0);
        }
        __syncthreads();
    }

    // ---- epilogue: plain stores, each output element written exactly once ----
#pragma unroll
    for (int rr = 0; rr < 4; ++rr) {
        int kc = mt * 32 + kcT * 16 + g4 * 4 + rr;
        Cout[((size_t)b * NKC + kc) * ND + dT * 16 + lm] = acc[rr];
    }
}

// ---------------------------------------------------------------------------
// attn_fused: x<8 -> MFMA attention rows x*32..+31 (bias + bf16 inline,
// max-free softmax); x>=8 -> mean-broadcast, 64 rows/block. grid (68, 32).
// ---------------------------------------------------------------------------
__global__ __launch_bounds__(256) void attn_fused(
    const float* __restrict__ Q,  const float* __restrict__ KeT,
    const float* __restrict__ Vf, const float* __restrict__ Eb,
    const float* __restrict__ Fb, float* __restrict__ out)
{
    const int x = blockIdx.x, b = blockIdx.y, t = threadIdx.x;

    if (x >= 8) {
        // rows >= 256 fully masked -> uniform softmax -> mean_k (Vf[k,:]+Fb[k])
        __shared__ float pq[16][64];
        __shared__ float mv[64];
        const int kg = t >> 4, dq = t & 15;
        float4 s4 = (float4){0.f, 0.f, 0.f, 0.f};
        for (int p = 0; p < 16; ++p) {
            int k = p * 16 + kg;
            float4 v = *(const float4*)&Vf[((size_t)b * NKC + k) * ND + dq * 4];
            float fb = Fb[k];
            s4.x += v.x + fb; s4.y += v.y + fb; s4.z += v.z + fb; s4.w += v.w + fb;
        }
        *(float4*)&pq[kg][dq * 4] = s4;
        __syncthreads();
        if (t < 64) {
            float m = 0.f;
#pragma unroll
            for (int i = 0; i < 16; ++i) m += pq[i][t];
            mv[t] = m * (1.f / 256.f);
        }
        __syncthreads();
        const int r0 = 256 + (x - 8) * 64;
#pragma unroll
        for (int i = 0; i < 4; ++i) {      // 4*256 float4 = 64 rows
            int idx = i * 256 + t, row = idx >> 4, q = idx & 15;
            *(float4*)&out[((size_t)b * NS + r0 + row) * ND + q * 4] =
                *(const float4*)&mv[q * 4];
        }
        return;
    }

    const int s0 = x * 32;
    const int wave = t >> 6, lane = t & 63, lm = lane & 15, g = lane >> 4;
    __shared__ short Qs[32 * QSTR];     //  4.6 KB
    __shared__ short PsB[32 * PBSTR];   // 16.9 KB
    __shared__ short VfT[64 * VSTR];    // 33.8 KB
    __shared__ float rsums[32][4];      // [row][wave]

    // stage Q rows -> bf16
    {
        int row = t >> 3, dq = t & 7;
        size_t off = ((size_t)b * NS + s0 + row) * ND + dq * 8;
        float4 q0 = *(const float4*)&Q[off], q1 = *(const float4*)&Q[off + 4];
        short8 w;
        w[0] = f2bf(q0.x); w[1] = f2bf(q0.y); w[2] = f2bf(q0.z); w[3] = f2bf(q0.w);
        w[4] = f2bf(q1.x); w[5] = f2bf(q1.y); w[6] = f2bf(q1.z); w[7] = f2bf(q1.w);
        *(short8*)&Qs[row * QSTR + dq * 8] = w;
    }
    // stage VfT[d][k] = bf16(Vf[k][d] + Fb[k]); 4 passes of 64 k-rows
    {
        const int dB = t & 31, sB = t >> 5;
#pragma unroll
        for (int pass = 0; pass < 4; ++pass) {
            int kb = pass * 64 + sB * 8;
            float2 v[8]; float fb[8];
#pragma unroll
            for (int i = 0; i < 8; ++i) {
                v[i]  = *(const float2*)&Vf[((size_t)b * NKC + kb + i) * ND + dB * 2];
                fb[i] = Fb[kb + i];
            }
            short8 w0, w1;
#pragma unroll
            for (int i = 0; i < 8; ++i) {
                w0[i] = f2bf(v[i].x + fb[i]);
                w1[i] = f2bf(v[i].y + fb[i]);
            }
            *(short8*)&VfT[(dB * 2 + 0) * VSTR + kb] = w0;
            *(short8*)&VfT[(dB * 2 + 1) * VSTR + kb] = w1;
        }
    }
    __syncthreads();

    // phase 1: P = Q*(Ke+Eb)^T/8; wave w -> col range [w*64, w*64+64)
    f32x4 accP[2][4];
#pragma unroll
    for (int rt = 0; rt < 2; ++rt)
#pragma unroll
        for (int kk = 0; kk < 4; ++kk) accP[rt][kk] = (f32x4){0.f, 0.f, 0.f, 0.f};
#pragma unroll
    for (int kk = 0; kk < 4; ++kk) {
        int kt = wave * 4 + kk;
        float ebv = Eb[kt * 16 + lm];
#pragma unroll
        for (int ks2 = 0; ks2 < 2; ++ks2) {
            const float* kp = &KeT[((size_t)b * NKC + kt * 16 + lm) * ND + ks2 * 32 + g * 8];
            float4 c0 = *(const float4*)kp, c1 = *(const float4*)(kp + 4);
            short8 bf;
            bf[0] = f2bf(c0.x + ebv); bf[1] = f2bf(c0.y + ebv);
            bf[2] = f2bf(c0.z + ebv); bf[3] = f2bf(c0.w + ebv);
            bf[4] = f2bf(c1.x + ebv); bf[5] = f2bf(c1.y + ebv);
            bf[6] = f2bf(c1.z + ebv); bf[7] = f2bf(c1.w + ebv);
#pragma unroll
            for (int rt = 0; rt < 2; ++rt) {
                short8 aq = *(const short8*)&Qs[(rt * 16 + lm) * QSTR + ks2 * 32 + g * 8];
                accP[rt][kk] = __builtin_amdgcn_mfma_f32_16x16x32_bf16(aq, bf, accP[rt][kk], 0, 0, 0);
            }
        }
    }
    // exp (max-free: scores ~ N(0,1), no overflow) + per-row partial sums
#pragma unroll
    for (int rt = 0; rt < 2; ++rt)
#pragma unroll
        for (int r = 0; r < 4; ++r) {
            float s = 0.f;
            int rowg = s0 + rt * 16 + g * 4 + r;
#pragma unroll
            for (int kk = 0; kk < 4; ++kk) {
                int col = wave * 64 + kk * 16 + lm;
                float e = (col >= rowg) ? __expf(accP[rt][kk][r] * 0.125f) : 0.f;
                accP[rt][kk][r] = e;
                s += e;
            }
#pragma unroll
            for (int off = 1; off <= 8; off <<= 1) s += __shfl_xor(s, off, 64);
            if (lm == 0) rsums[rt * 16 + g * 4 + r][wave] = s;
        }
    __syncthreads();
    // normalize -> PsB bf16
#pragma unroll
    for (int rt = 0; rt < 2; ++rt)
#pragma unroll
        for (int r = 0; r < 4; ++r) {
            float4 rs = *(const float4*)&rsums[rt * 16 + g * 4 + r][0];
            float inv = 1.f / (rs.x + rs.y + rs.z + rs.w);
#pragma unroll
            for (int kk = 0; kk < 4; ++kk)
                PsB[(rt * 16 + g * 4 + r) * PBSTR + wave * 64 + kk * 16 + lm] =
                    f2bf(accP[rt][kk][r] * inv);
        }
    __syncthreads();

    // phase 2: out = P * VfT; k < 32x provably zero -> start at ks = x
    f32x4 oa[2];
    oa[0] = (f32x4){0.f, 0.f, 0.f, 0.f};
    oa[1] = (f32x4){0.f, 0.f, 0.f, 0.f};
    for (int ks = x; ks < 8; ++ks) {
        short8 bv = *(const short8*)&VfT[(wave * 16 + lm) * VSTR + ks * 32 + g * 8];
#pragma unroll
        for (int rt = 0; rt < 2; ++rt) {
            short8 av = *(const short8*)&PsB[(rt * 16 + lm) * PBSTR + ks * 32 + g * 8];
            oa[rt] = __builtin_amdgcn_mfma_f32_16x16x32_bf16(av, bv, oa[rt], 0, 0, 0);
        }
    }
#pragma unroll
    for (int rt = 0; rt < 2; ++rt)
#pragma unroll
        for (int r = 0; r < 4; ++r)
            out[((size_t)b * NS + s0 + rt * 16 + g * 4 + r) * ND + wave * 16 + lm] = oa[rt][r];
}

extern "C" void kernel_launch(void* const* d_in, const int* in_sizes, int n_in,
                              void* d_out, int out_size, void* d_ws, size_t ws_size,
                              hipStream_t stream) {
    (void)in_sizes; (void)n_in; (void)out_size;
    const float* Q  = (const float*)d_in[0];
    const float* K  = (const float*)d_in[1];
    const float* V  = (const float*)d_in[2];
    const float* Ew = (const float*)d_in[3];
    const float* Eb = (const float*)d_in[4];
    const float* Fw = (const float*)d_in[5];
    const float* Fb = (const float*)d_in[6];
    float* out = (float*)d_out;

    const size_t nKe = (size_t)NB * NKC * ND;       // 524288
    float* KeT = (float*)d_ws;                      // 2 MB fp32 (written once)
    float* Vf  = KeT + nKe;                         // 2 MB fp32 (written once)

    if (ws_size >= 8u * 1024 * 1024) {
        short* EwB = (short*)(Vf + nKe);            // 2 MB bf16 weights
        short* FwB = EwB + (size_t)NKC * NS;        // 2 MB bf16 weights
        prep<<<dim3(1024), 256, 0, stream>>>(Ew, Fw, EwB, FwB);
        proj_gemm<short><<<dim3(512), 512, 0, stream>>>(EwB, FwB, K, V, KeT, Vf);
    } else {
        // no zero-init needed: proj writes every output element exactly once
        proj_gemm<float><<<dim3(512), 512, 0, stream>>>(Ew, Fw, K, V, KeT, Vf);
    }
    attn_fused<<<dim3(68, NB), 256, 0, stream>>>(Q, KeT, Vf, Eb, Fb, out);
}

// Round 4
// 185.629 us; speedup vs baseline: 1.0523x; 1.0411x over previous
//
#include <hip/hip_runtime.h>
#include <hip/hip_bf16.h>
#include <math.h>

#define NB  32
#define NS  4096
#define ND  64
#define NKC 256

// proj tiling: 512 blocks x 256 threads, block tile 64kc x 64d, K split in 2
#define BK   128   // K (seq) step per iteration
#define KHALF 2048
#define ASA  132   // As row stride (shorts): 128 data + 4 pad
#define ASB  132   // Bs row stride (shorts)

// attn_fused LDS strides (unchanged)
#define QSTR  72
#define PBSTR 264
#define VSTR  264

typedef __attribute__((ext_vector_type(8))) short short8;
typedef __attribute__((ext_vector_type(4))) float f32x4;

__device__ __forceinline__ short f2bf(float f) {
    union { float f; unsigned u; } v; v.f = f;
    return (short)((v.u + 0x7FFFu + ((v.u >> 16) & 1u)) >> 16);  // RTNE
}

// ---------------------------------------------------------------------------
// prep (ws>=12MB only): convert Ew/Fw fp32 -> bf16.
// ---------------------------------------------------------------------------
__global__ __launch_bounds__(256) void prep(
    const float* __restrict__ Ew, const float* __restrict__ Fw,
    short* __restrict__ EwB, short* __restrict__ FwB)
{
    const int gid = blockIdx.x * 256 + threadIdx.x;       // < 262144
    const int half = (NKC * NS) / 8;                      // 131072
    const float* src = (gid < half) ? Ew : Fw;
    short* dst       = (gid < half) ? EwB : FwB;
    const int i8 = (gid < half) ? gid : gid - half;
    float4 a = *(const float4*)&src[(size_t)i8 * 8];
    float4 c = *(const float4*)&src[(size_t)i8 * 8 + 4];
    short8 w;
    w[0] = f2bf(a.x); w[1] = f2bf(a.y); w[2] = f2bf(a.z); w[3] = f2bf(a.w);
    w[4] = f2bf(c.x); w[5] = f2bf(c.y); w[6] = f2bf(c.z); w[7] = f2bf(c.w);
    *(short8*)&dst[(size_t)i8 * 8] = w;
}

// ---------------------------------------------------------------------------
// proj v4: split-K=2, no atomics. 512 blocks x 256 thr = 2 blocks/CU
// (8 waves/CU, barrier-independent blocks overlap each other's stalls).
// Block tile = 64 kc x 64 d over one K-half (16 iters of BK=128) -> keeps
// R2's proven reuse ratios (B staged 4x per (b,mm,kh), 1.25KB LDS-read/MFMA).
//
// bid = gq*32 + mt*8 + r8; grp = gq*8 + r8 = ((b*2+mm)*2+kh):
//  - 4 mt-sharers of one B half-slab have equal bid%8 -> same XCD,
//    B (512KB fp32) fetched once per XCD, L2-served to 4 sharers.
//  - bid%8 fixes (kh, mm, b&1): each XCD streams one matrix & one K-half;
//    its A working set (256 x 2048) is L2-resident.
// Partial sums -> plain stores into per-half buffers; reduce2 adds them.
// ---------------------------------------------------------------------------
template <typename AT>
__global__ __launch_bounds__(256, 2) void proj_sk(
    const AT* __restrict__ EwX, const AT* __restrict__ FwX,
    const float* __restrict__ K, const float* __restrict__ V,
    float* __restrict__ KeTa, float* __restrict__ Vfa,
    float* __restrict__ KeTb, float* __restrict__ Vfb)
{
    const int bid = blockIdx.x;
    const int r8 = bid & 7, mt = (bid >> 3) & 3, gq = bid >> 5;  // gq 0..15
    const int grp = gq * 8 + r8;                                 // 0..127
    const int kh = grp & 1, mm = (grp >> 1) & 1, b = grp >> 2;

    const AT* __restrict__ Ab    = mm ? FwX : EwX;  // [256][4096]
    const float* __restrict__ Bg = mm ? V   : K;    // [B][4096][64] fp32
    float* __restrict__ Cout = kh ? (mm ? Vfb : KeTb) : (mm ? Vfa : KeTa);

    const int t = threadIdx.x, wave = t >> 6, lane = t & 63;
    const int lm = lane & 15, g4 = lane >> 4;
    __shared__ short As[64 * ASA];   // 16896 B, rows = kc (local), cols = s
    __shared__ short Bs[64 * ASB];   // 16896 B, rows = d,          cols = s
    const size_t bBase = (size_t)b * NS * ND;
    const size_t aBase = (size_t)mt * 64 * NS;
    const int rA = t >> 4, jA = t & 15;  // A staging: 16 rows/pass, 16 col-octets
    const int dB = t & 31, sB = t >> 5;  // B staging: d-pair, s-octet group

    f32x4 acc[4];
#pragma unroll
    for (int nt = 0; nt < 4; ++nt) acc[nt] = (f32x4){0.f, 0.f, 0.f, 0.f};

    short8 pa[4];      // bf16-A path
    float4 paf[8];     // fp32-A path
    float2 pb[16];     // B: 16 s-rows' d-pairs

    const int sBeg = kh * KHALF, sEnd = sBeg + KHALF;

    // prologue prefetch (iter 0)
#pragma unroll
    for (int i = 0; i < 4; ++i) {
        if constexpr (sizeof(AT) == 2) {
            pa[i] = *(const short8*)&Ab[aBase + (size_t)(i * 16 + rA) * NS + sBeg + jA * 8];
        } else {
            paf[2 * i]     = *(const float4*)&Ab[aBase + (size_t)(i * 16 + rA) * NS + sBeg + jA * 8];
            paf[2 * i + 1] = *(const float4*)&Ab[aBase + (size_t)(i * 16 + rA) * NS + sBeg + jA * 8 + 4];
        }
    }
#pragma unroll
    for (int h = 0; h < 2; ++h)
#pragma unroll
        for (int i = 0; i < 8; ++i)
            pb[h * 8 + i] = *(const float2*)&Bg[bBase + (size_t)(sBeg + h * 64 + sB * 8 + i) * ND + dB * 2];

    for (int s0 = sBeg; s0 < sEnd; s0 += BK) {
        // ---- stage regs -> LDS ----
#pragma unroll
        for (int i = 0; i < 4; ++i) {
            if constexpr (sizeof(AT) == 2) {
                *(short8*)&As[(i * 16 + rA) * ASA + jA * 8] = pa[i];
            } else {
                short8 w;
                w[0] = f2bf(paf[2 * i].x);     w[1] = f2bf(paf[2 * i].y);
                w[2] = f2bf(paf[2 * i].z);     w[3] = f2bf(paf[2 * i].w);
                w[4] = f2bf(paf[2 * i + 1].x); w[5] = f2bf(paf[2 * i + 1].y);
                w[6] = f2bf(paf[2 * i + 1].z); w[7] = f2bf(paf[2 * i + 1].w);
                *(short8*)&As[(i * 16 + rA) * ASA + jA * 8] = w;
            }
        }
#pragma unroll
        for (int h = 0; h < 2; ++h) {
            short8 w0, w1;
#pragma unroll
            for (int i = 0; i < 8; ++i) {
                w0[i] = f2bf(pb[h * 8 + i].x);
                w1[i] = f2bf(pb[h * 8 + i].y);
            }
            *(short8*)&Bs[(dB * 2 + 0) * ASB + h * 64 + sB * 8] = w0;
            *(short8*)&Bs[(dB * 2 + 1) * ASB + h * 64 + sB * 8] = w1;
        }
        __syncthreads();

        // ---- issue next-iter global loads (land during MFMA below) ----
        if (s0 + BK < sEnd) {
            const int sn = s0 + BK;
#pragma unroll
            for (int i = 0; i < 4; ++i) {
                if constexpr (sizeof(AT) == 2) {
                    pa[i] = *(const short8*)&Ab[aBase + (size_t)(i * 16 + rA) * NS + sn + jA * 8];
                } else {
                    paf[2 * i]     = *(const float4*)&Ab[aBase + (size_t)(i * 16 + rA) * NS + sn + jA * 8];
                    paf[2 * i + 1] = *(const float4*)&Ab[aBase + (size_t)(i * 16 + rA) * NS + sn + jA * 8 + 4];
                }
            }
#pragma unroll
            for (int h = 0; h < 2; ++h)
#pragma unroll
                for (int i = 0; i < 8; ++i)
                    pb[h * 8 + i] = *(const float2*)&Bg[bBase + (size_t)(sn + h * 64 + sB * 8 + i) * ND + dB * 2];
        }

        // ---- MFMA over BK=128 (4 k-steps of 32) ----
#pragma unroll
        for (int ks = 0; ks < BK; ks += 32) {
            short8 aF = *(const short8*)&As[(wave * 16 + lm) * ASA + ks + g4 * 8];
#pragma unroll
            for (int nt = 0; nt < 4; ++nt) {
                short8 bF = *(const short8*)&Bs[(nt * 16 + lm) * ASB + ks + g4 * 8];
                acc[nt] = __builtin_amdgcn_mfma_f32_16x16x32_bf16(aF, bF, acc[nt], 0, 0, 0);
            }
        }
        __syncthreads();
    }

    // ---- epilogue: plain stores into this half's buffer ----
#pragma unroll
    for (int nt = 0; nt < 4; ++nt)
#pragma unroll
        for (int rr = 0; rr < 4; ++rr) {
            int kc = mt * 64 + wave * 16 + g4 * 4 + rr;
            Cout[((size_t)b * NKC + kc) * ND + nt * 16 + lm] = acc[nt][rr];
        }
}

// ---------------------------------------------------------------------------
// reduce2: A-region += B-region (elementwise), 262144 float4 = 4 MB added
// into [KeT_a|Vf_a]. 1024 blocks x 256 threads.
// ---------------------------------------------------------------------------
__global__ __launch_bounds__(256) void reduce2(
    float4* __restrict__ Areg, const float4* __restrict__ Breg)
{
    const int gid = blockIdx.x * 256 + threadIdx.x;   // < 262144
    float4 a = Areg[gid], c = Breg[gid];
    Areg[gid] = (float4){a.x + c.x, a.y + c.y, a.z + c.z, a.w + c.w};
}

// ---------------------------------------------------------------------------
// attn_fused: x<8 -> MFMA attention rows x*32..+31 (bias + bf16 inline,
// max-free softmax); x>=8 -> mean-broadcast, 64 rows/block. grid (68, 32).
// (unchanged)
// ---------------------------------------------------------------------------
__global__ __launch_bounds__(256) void attn_fused(
    const float* __restrict__ Q,  const float* __restrict__ KeT,
    const float* __restrict__ Vf, const float* __restrict__ Eb,
    const float* __restrict__ Fb, float* __restrict__ out)
{
    const int x = blockIdx.x, b = blockIdx.y, t = threadIdx.x;

    if (x >= 8) {
        __shared__ float pq[16][64];
        __shared__ float mv[64];
        const int kg = t >> 4, dq = t & 15;
        float4 s4 = (float4){0.f, 0.f, 0.f, 0.f};
        for (int p = 0; p < 16; ++p) {
            int k = p * 16 + kg;
            float4 v = *(const float4*)&Vf[((size_t)b * NKC + k) * ND + dq * 4];
            float fb = Fb[k];
            s4.x += v.x + fb; s4.y += v.y + fb; s4.z += v.z + fb; s4.w += v.w + fb;
        }
        *(float4*)&pq[kg][dq * 4] = s4;
        __syncthreads();
        if (t < 64) {
            float m = 0.f;
#pragma unroll
            for (int i = 0; i < 16; ++i) m += pq[i][t];
            mv[t] = m * (1.f / 256.f);
        }
        __syncthreads();
        const int r0 = 256 + (x - 8) * 64;
#pragma unroll
        for (int i = 0; i < 4; ++i) {
            int idx = i * 256 + t, row = idx >> 4, q = idx & 15;
            *(float4*)&out[((size_t)b * NS + r0 + row) * ND + q * 4] =
                *(const float4*)&mv[q * 4];
        }
        return;
    }

    const int s0 = x * 32;
    const int wave = t >> 6, lane = t & 63, lm = lane & 15, g = lane >> 4;
    __shared__ short Qs[32 * QSTR];
    __shared__ short PsB[32 * PBSTR];
    __shared__ short VfT[64 * VSTR];
    __shared__ float rsums[32][4];

    {
        int row = t >> 3, dq = t & 7;
        size_t off = ((size_t)b * NS + s0 + row) * ND + dq * 8;
        float4 q0 = *(const float4*)&Q[off], q1 = *(const float4*)&Q[off + 4];
        short8 w;
        w[0] = f2bf(q0.x); w[1] = f2bf(q0.y); w[2] = f2bf(q0.z); w[3] = f2bf(q0.w);
        w[4] = f2bf(q1.x); w[5] = f2bf(q1.y); w[6] = f2bf(q1.z); w[7] = f2bf(q1.w);
        *(short8*)&Qs[row * QSTR + dq * 8] = w;
    }
    {
        const int dB = t & 31, sB = t >> 5;
#pragma unroll
        for (int pass = 0; pass < 4; ++pass) {
            int kb = pass * 64 + sB * 8;
            float2 v[8]; float fb[8];
#pragma unroll
            for (int i = 0; i < 8; ++i) {
                v[i]  = *(const float2*)&Vf[((size_t)b * NKC + kb + i) * ND + dB * 2];
                fb[i] = Fb[kb + i];
            }
            short8 w0, w1;
#pragma unroll
            for (int i = 0; i < 8; ++i) {
                w0[i] = f2bf(v[i].x + fb[i]);
                w1[i] = f2bf(v[i].y + fb[i]);
            }
            *(short8*)&VfT[(dB * 2 + 0) * VSTR + kb] = w0;
            *(short8*)&VfT[(dB * 2 + 1) * VSTR + kb] = w1;
        }
    }
    __syncthreads();

    f32x4 accP[2][4];
#pragma unroll
    for (int rt = 0; rt < 2; ++rt)
#pragma unroll
        for (int kk = 0; kk < 4; ++kk) accP[rt][kk] = (f32x4){0.f, 0.f, 0.f, 0.f};
#pragma unroll
    for (int kk = 0; kk < 4; ++kk) {
        int kt = wave * 4 + kk;
        float ebv = Eb[kt * 16 + lm];
#pragma unroll
        for (int ks2 = 0; ks2 < 2; ++ks2) {
            const float* kp = &KeT[((size_t)b * NKC + kt * 16 + lm) * ND + ks2 * 32 + g * 8];
            float4 c0 = *(const float4*)kp, c1 = *(const float4*)(kp + 4);
            short8 bf;
            bf[0] = f2bf(c0.x + ebv); bf[1] = f2bf(c0.y + ebv);
            bf[2] = f2bf(c0.z + ebv); bf[3] = f2bf(c0.w + ebv);
            bf[4] = f2bf(c1.x + ebv); bf[5] = f2bf(c1.y + ebv);
            bf[6] = f2bf(c1.z + ebv); bf[7] = f2bf(c1.w + ebv);
#pragma unroll
            for (int rt = 0; rt < 2; ++rt) {
                short8 aq = *(const short8*)&Qs[(rt * 16 + lm) * QSTR + ks2 * 32 + g * 8];
                accP[rt][kk] = __builtin_amdgcn_mfma_f32_16x16x32_bf16(aq, bf, accP[rt][kk], 0, 0, 0);
            }
        }
    }
#pragma unroll
    for (int rt = 0; rt < 2; ++rt)
#pragma unroll
        for (int r = 0; r < 4; ++r) {
            float s = 0.f;
            int rowg = s0 + rt * 16 + g * 4 + r;
#pragma unroll
            for (int kk = 0; kk < 4; ++kk) {
                int col = wave * 64 + kk * 16 + lm;
                float e = (col >= rowg) ? __expf(accP[rt][kk][r] * 0.125f) : 0.f;
                accP[rt][kk][r] = e;
                s += e;
            }
#pragma unroll
            for (int off = 1; off <= 8; off <<= 1) s += __shfl_xor(s, off, 64);
            if (lm == 0) rsums[rt * 16 + g * 4 + r][wave] = s;
        }
    __syncthreads();
#pragma unroll
    for (int rt = 0; rt < 2; ++rt)
#pragma unroll
        for (int r = 0; r < 4; ++r) {
            float4 rs = *(const float4*)&rsums[rt * 16 + g * 4 + r][0];
            float inv = 1.f / (rs.x + rs.y + rs.z + rs.w);
#pragma unroll
            for (int kk = 0; kk < 4; ++kk)
                PsB[(rt * 16 + g * 4 + r) * PBSTR + wave * 64 + kk * 16 + lm] =
                    f2bf(accP[rt][kk][r] * inv);
        }
    __syncthreads();

    f32x4 oa[2];
    oa[0] = (f32x4){0.f, 0.f, 0.f, 0.f};
    oa[1] = (f32x4){0.f, 0.f, 0.f, 0.f};
    for (int ks = x; ks < 8; ++ks) {
        short8 bv = *(const short8*)&VfT[(wave * 16 + lm) * VSTR + ks * 32 + g * 8];
#pragma unroll
        for (int rt = 0; rt < 2; ++rt) {
            short8 av = *(const short8*)&PsB[(rt * 16 + lm) * PBSTR + ks * 32 + g * 8];
            oa[rt] = __builtin_amdgcn_mfma_f32_16x16x32_bf16(av, bv, oa[rt], 0, 0, 0);
        }
    }
#pragma unroll
    for (int rt = 0; rt < 2; ++rt)
#pragma unroll
        for (int r = 0; r < 4; ++r)
            out[((size_t)b * NS + s0 + rt * 16 + g * 4 + r) * ND + wave * 16 + lm] = oa[rt][r];
}

extern "C" void kernel_launch(void* const* d_in, const int* in_sizes, int n_in,
                              void* d_out, int out_size, void* d_ws, size_t ws_size,
                              hipStream_t stream) {
    (void)in_sizes; (void)n_in; (void)out_size;
    const float* Q  = (const float*)d_in[0];
    const float* K  = (const float*)d_in[1];
    const float* V  = (const float*)d_in[2];
    const float* Ew = (const float*)d_in[3];
    const float* Eb = (const float*)d_in[4];
    const float* Fw = (const float*)d_in[5];
    const float* Fb = (const float*)d_in[6];
    float* out = (float*)d_out;

    const size_t nKe = (size_t)NB * NKC * ND;       // 524288 floats (2 MB)
    float* base = (float*)d_ws;
    float* KeTa = base;                             // [0, 2 MB)
    float* Vfa  = base + nKe;                       // [2, 4 MB)
    float* KeTb = base + 2 * nKe;                   // [4, 6 MB)
    float* Vfb  = base + 3 * nKe;                   // [6, 8 MB)

    if (ws_size >= 12u * 1024 * 1024) {
        // extra room: preconvert weights to bf16 (halves A traffic + VALU)
        short* EwB = (short*)(base + 4 * nKe);      // [8, 10 MB)
        short* FwB = EwB + (size_t)NKC * NS;        // [10, 12 MB)
        prep<<<dim3(1024), 256, 0, stream>>>(Ew, Fw, EwB, FwB);
        proj_sk<short><<<dim3(512), 256, 0, stream>>>(EwB, FwB, K, V,
                                                      KeTa, Vfa, KeTb, Vfb);
    } else {
        // 8 MB budget: convert A in staging (no prep kernel needed)
        proj_sk<float><<<dim3(512), 256, 0, stream>>>(Ew, Fw, K, V,
                                                      KeTa, Vfa, KeTb, Vfb);
    }
    reduce2<<<dim3(1024), 256, 0, stream>>>((float4*)base,
                                            (const float4*)(base + 2 * nKe));
    attn_fused<<<dim3(68, NB), 256, 0, stream>>>(Q, KeTa, Vfa, Eb, Fb, out);
}